// Round 6
// baseline (1132.034 us; speedup 1.0000x reference)
//
#include <hip/hip_runtime.h>

#define BINS 256
#define HWPIX (512 * 512)     // pixels per channel
#define NCH 192               // B*C = 64*3
#define BPC 32                // blocks per channel
#define NBLK (NCH * BPC)      // 6144 blocks, 256 threads, 8192 px/block

typedef float f4v __attribute__((ext_vector_type(4)));

// Workspace layout:
//   [ done:  NCH u32 ]  (ticket counters, zeroed each launch)
//   [ ready: NCH u32 ]  (LUT-published flags, zeroed each launch)
//   [ pad to 4 KiB ]
//   [ pws:  NBLK*BINS int  (per-block partial histograms, overwritten) ]
//   [ glut: NCH*BINS float (pre-divided LUTs, overwritten) ]
#define FLAGS_BYTES ((size_t)4096)
#define PWS_BYTES   ((size_t)NBLK * BINS * sizeof(int))

// Single-dispatch fused equalize with channel-local producer/consumer sync.
// Each block: quantize 8192 px (packed u8 kept in 8 VGPRs) + LDS hist ->
// partial hist -> per-channel ticket. Last block of the channel reduces the
// 32 partials, computes the LUT (bit-exact w/ reference), publishes it.
// Everyone spins on the channel flag (not a global barrier), then applies
// from registers. Input read once (NT), output written once (NT).
__global__ __launch_bounds__(256, 6) void equalize_fused(const float* __restrict__ x,
                                                         float* __restrict__ out,
                                                         unsigned int* __restrict__ done,
                                                         unsigned int* __restrict__ ready,
                                                         int* __restrict__ pws,
                                                         float* __restrict__ glut) {
    __shared__ int   h[BINS];
    __shared__ int   cum[BINS];
    __shared__ int   red[BINS];
    __shared__ float lutf[BINS];
    __shared__ unsigned int ticket_s;

    const int t   = threadIdx.x;
    const int ch  = blockIdx.x >> 5;
    const int blk = blockIdx.x & 31;

    h[t] = 0;
    __syncthreads();

    const f4v* in4  = (const f4v*)(x + (size_t)ch * HWPIX);
    f4v*       out4 = (f4v*)(out + (size_t)ch * HWPIX);
    const int idx0 = blk * 2048 + t;

    unsigned int packed[8];

    // ---- Phase 1: read once, quantize, LDS histogram, keep bins in regs ----
#pragma unroll
    for (int i = 0; i < 8; ++i) {
        const int k = idx0 + i * 256;
        f4v v = __builtin_nontemporal_load(&in4[k]);
        int b0 = (int)fminf(fmaxf(floorf(v.x * 255.0f), 0.0f), 255.0f);
        int b1 = (int)fminf(fmaxf(floorf(v.y * 255.0f), 0.0f), 255.0f);
        int b2 = (int)fminf(fmaxf(floorf(v.z * 255.0f), 0.0f), 255.0f);
        int b3 = (int)fminf(fmaxf(floorf(v.w * 255.0f), 0.0f), 255.0f);
        packed[i] = (unsigned int)b0 | ((unsigned int)b1 << 8) |
                    ((unsigned int)b2 << 16) | ((unsigned int)b3 << 24);
        atomicAdd(&h[b0], 1);
        atomicAdd(&h[b1], 1);
        atomicAdd(&h[b2], 1);
        atomicAdd(&h[b3], 1);
    }
    __syncthreads();

    // publish partial histogram, then take the channel ticket
    pws[(size_t)blockIdx.x * BINS + t] = h[t];
    __threadfence();                               // device-scope: pws visible
    if (t == 0) {
        ticket_s = __hip_atomic_fetch_add(&done[ch], 1u, __ATOMIC_ACQ_REL,
                                          __HIP_MEMORY_SCOPE_AGENT);
    }
    __syncthreads();

    // ---- Phase 2: last-arriving block computes the channel LUT ----
    if (ticket_s == BPC - 1) {
        const int* base = pws + (size_t)ch * BPC * BINS;
        int s = 0;
#pragma unroll
        for (int b = 0; b < BPC; ++b) s += base[b * BINS + t];
        h[t]   = s;
        cum[t] = s;
        red[t] = (s > 0) ? t : -1;
        __syncthreads();

        for (int off = 128; off > 0; off >>= 1) {  // last nonzero bin index
            if (t < off) red[t] = max(red[t], red[t + off]);
            __syncthreads();
        }
        for (int off = 1; off < BINS; off <<= 1) { // inclusive scan
            int v = cum[t];
            int a = (t >= off) ? cum[t - off] : 0;
            __syncthreads();
            cum[t] = v + a;
            __syncthreads();
        }

        const int last = h[red[0]];
        const int step = (HWPIX - last) / 255;
        int lutv;
        if (step == 0) {
            lutv = t;                              // identity channel
        } else if (t == 0) {
            lutv = 0;                              // shifted-right-by-one head
        } else {
            int val = (cum[t - 1] + (step >> 1)) / step;
            lutv = min(max(val, 0), 255);
        }
        glut[ch * BINS + t] = (float)lutv / 255.0f; // pre-divide (bit-exact)
        __syncthreads();                            // all 256 stores issued+drained
        if (t == 0) {
            __threadfence();                        // device-scope: glut visible
            __hip_atomic_store(&ready[ch], 1u, __ATOMIC_RELEASE,
                               __HIP_MEMORY_SCOPE_AGENT);
        }
    }

    // ---- wait for this channel's LUT (channel-local, not grid-wide) ----
    if (t == 0) {
        while (__hip_atomic_load(&ready[ch], __ATOMIC_ACQUIRE,
                                 __HIP_MEMORY_SCOPE_AGENT) == 0u) {
            __builtin_amdgcn_s_sleep(2);
        }
    }
    __syncthreads();
    lutf[t] = glut[ch * BINS + t];
    __syncthreads();

    // ---- Phase 3: apply from registers, stream output ----
#pragma unroll
    for (int i = 0; i < 8; ++i) {
        const int k = idx0 + i * 256;
        const unsigned int p = packed[i];
        f4v o;
        o.x = lutf[p & 255u];
        o.y = lutf[(p >> 8) & 255u];
        o.z = lutf[(p >> 16) & 255u];
        o.w = lutf[p >> 24];
        __builtin_nontemporal_store(o, &out4[k]);
    }
}

extern "C" void kernel_launch(void* const* d_in, const int* in_sizes, int n_in,
                              void* d_out, int out_size, void* d_ws, size_t ws_size,
                              hipStream_t stream) {
    const float* x = (const float*)d_in[0];
    float* out = (float*)d_out;

    unsigned int* done  = (unsigned int*)d_ws;
    unsigned int* ready = done + NCH;
    int*   pws  = (int*)((char*)d_ws + FLAGS_BYTES);
    float* glut = (float*)((char*)d_ws + FLAGS_BYTES + PWS_BYTES);

    // zero the tiny flag arrays (part of the captured graph, runs every replay)
    hipMemsetAsync(d_ws, 0, 2 * NCH * sizeof(unsigned int), stream);

    equalize_fused<<<NBLK, 256, 0, stream>>>(x, out, done, ready, pws, glut);
}

// Round 7
// 123.573 us; speedup vs baseline: 9.1609x; 9.1609x over previous
//
#include <hip/hip_runtime.h>

#define BINS 256
#define HWPIX (512 * 512)     // pixels per channel
#define NCH 192               // B*C = 64*3
#define BPC 8                 // blocks per channel
#define NBLK (NCH * BPC)      // 1536 = 6 blocks/CU * 256 CUs  (exact residency)
#define F4PT 32               // float4 per thread: 8192 f4/block * 8 = 65536 = HWPIX/4

typedef float f4v __attribute__((ext_vector_type(4)));

// Workspace: [ bar u32 @0 ][ rel u32 @256B ][ pad to 4KiB ][ ghist NCH*BINS int ]
// All zeroed by the memset each launch (graph replays it).
#define FLAGS_BYTES ((size_t)4096)
#define GHIST_BYTES ((size_t)NCH * BINS * sizeof(int))

// Single-dispatch equalize with a hand-rolled grid barrier.
// RULES (learned round 6): cross-XCD communication uses atomic RMW ONLY —
// RMWs execute at the fabric coherence point (cross-XCD-correct, m20) and
// cost no L2 invalidation. Never plain/acquire loads on flag or hist data:
// acquire-loads invalidate the whole local L2 per poll (the 1.2 ms disaster),
// and relaxed loads can cache a stale line and spin forever.
__global__ __launch_bounds__(256, 6) void equalize_onepass(const float* __restrict__ x,
                                                           float* __restrict__ out,
                                                           unsigned int* __restrict__ bar,
                                                           unsigned int* __restrict__ rel,
                                                           int* __restrict__ ghist) {
    __shared__ int   h[BINS];
    __shared__ int   cum[BINS];
    __shared__ int   red[BINS];
    __shared__ float lutf[BINS];

    const int t   = threadIdx.x;
    const int ch  = blockIdx.x >> 3;    // 8 blocks per channel
    const int blk = blockIdx.x & 7;

    h[t] = 0;
    __syncthreads();

    const f4v* in4  = (const f4v*)(x + (size_t)ch * HWPIX);
    f4v*       out4 = (f4v*)(out + (size_t)ch * HWPIX);
    const int idx0 = blk * 8192 + t;    // 8192 f4 per block, stride-256 within

    unsigned int packed[F4PT];          // 32 u32 = 128 px, fully unrolled

    // ---- Phase 1: read once (NT), quantize, LDS histogram ----
#pragma unroll
    for (int i = 0; i < F4PT; ++i) {
        const int k = idx0 + i * 256;
        f4v v = __builtin_nontemporal_load(&in4[k]);
        int b0 = (int)fminf(fmaxf(floorf(v.x * 255.0f), 0.0f), 255.0f);
        int b1 = (int)fminf(fmaxf(floorf(v.y * 255.0f), 0.0f), 255.0f);
        int b2 = (int)fminf(fmaxf(floorf(v.z * 255.0f), 0.0f), 255.0f);
        int b3 = (int)fminf(fmaxf(floorf(v.w * 255.0f), 0.0f), 255.0f);
        packed[i] = (unsigned int)b0 | ((unsigned int)b1 << 8) |
                    ((unsigned int)b2 << 16) | ((unsigned int)b3 << 24);
        atomicAdd(&h[b0], 1);
        atomicAdd(&h[b1], 1);
        atomicAdd(&h[b2], 1);
        atomicAdd(&h[b3], 1);
    }
    __syncthreads();

    // publish to the channel histogram (fabric-executed device atomics)
    atomicAdd(&ghist[ch * BINS + t], h[t]);
    __syncthreads();   // compiler drains vmcnt before s_barrier -> hist RMWs issued & done

    // ---- grid barrier: atomics only, s_sleep backoff ----
    if (t == 0) {
        unsigned int old = atomicAdd(bar, 1u);
        if (old == (unsigned int)(NBLK - 1)) {
            atomicExch(rel, 1u);                       // release
        } else {
            while (atomicAdd(rel, 0u) == 0u) {         // authoritative RMW poll
                __builtin_amdgcn_s_sleep(8);
            }
        }
    }
    __syncthreads();

    // ---- Phase 2: every block computes its channel's LUT (redundant, cheap) ----
    // Read hist via RMW (belt-and-braces: never a stale L2 line).
    const int hv = atomicAdd(&ghist[ch * BINS + t], 0);
    h[t]   = hv;
    cum[t] = hv;
    red[t] = (hv > 0) ? t : -1;
    __syncthreads();

    for (int off = 128; off > 0; off >>= 1) {          // last nonzero bin index
        if (t < off) red[t] = max(red[t], red[t + off]);
        __syncthreads();
    }
    for (int off = 1; off < BINS; off <<= 1) {         // inclusive scan
        int v = cum[t];
        int a = (t >= off) ? cum[t - off] : 0;
        __syncthreads();
        cum[t] = v + a;
        __syncthreads();
    }

    const int last = h[red[0]];
    const int step = (HWPIX - last) / 255;
    int lutv;
    if (step == 0) {
        lutv = t;                                      // identity channel
    } else if (t == 0) {
        lutv = 0;                                      // shifted-right-by-one head
    } else {
        int val = (cum[t - 1] + (step >> 1)) / step;
        lutv = min(max(val, 0), 255);
    }
    lutf[t] = (float)lutv / 255.0f;                    // pre-divide (bit-exact w/ ref)
    __syncthreads();

    // ---- Phase 3: apply from registers, NT-stream the output ----
#pragma unroll
    for (int i = 0; i < F4PT; ++i) {
        const int k = idx0 + i * 256;
        const unsigned int p = packed[i];
        f4v o;
        o.x = lutf[p & 255u];
        o.y = lutf[(p >> 8) & 255u];
        o.z = lutf[(p >> 16) & 255u];
        o.w = lutf[p >> 24];
        __builtin_nontemporal_store(o, &out4[k]);
    }
}

extern "C" void kernel_launch(void* const* d_in, const int* in_sizes, int n_in,
                              void* d_out, int out_size, void* d_ws, size_t ws_size,
                              hipStream_t stream) {
    const float* x = (const float*)d_in[0];
    float* out = (float*)d_out;

    unsigned int* bar = (unsigned int*)d_ws;
    unsigned int* rel = (unsigned int*)((char*)d_ws + 256);
    int* ghist = (int*)((char*)d_ws + FLAGS_BYTES);

    // zero flags + ghist every launch (captured into the graph)
    hipMemsetAsync(d_ws, 0, FLAGS_BYTES + GHIST_BYTES, stream);

    equalize_onepass<<<NBLK, 256, 0, stream>>>(x, out, bar, rel, ghist);
}